// Round 8
// baseline (149.554 us; speedup 1.0000x reference)
//
#include <hip/hip_runtime.h>
#include <hip/hip_bf16.h>
#include <math.h>

#define DIM   5120
#define NH    40
#define NKV   8
#define HD    128
#define BS    8
#define KLEN  4096
#define NEWT  4095
#define NREP  5

#define ODQKV 7168          // 5120 + 1024 + 1024 combined output columns
#define NKC   32            // split-K chunks for GEMVs
#define KCH   (DIM / NKC)   // 160 rows per chunk

#define NCHB  64                // t-chunks per batch = blocks per batch
#define CH_T  (KLEN / NCHB)     // 64 t per block
#define NPART NCHB              // partials per (b,h)

// workspace layout (in floats)
#define WS_Q       0
#define WS_K       (WS_Q + BS * DIM)        // 40960
#define WS_V       (WS_K + BS * NKV * HD)   // 49152
#define WS_ATTN    (WS_V + BS * NKV * HD)   // 57344
#define WS_SCRATCH (WS_ATTN + BS * DIM)     // 98304  (scratch reused across phases)

// ---------------------------------------------------------------------------
// Phase A: combined QKV GEMV, split-K partials. 2 cols/thread, float2 weight
// loads, x via wave-uniform scalar loads.
// ---------------------------------------------------------------------------
__global__ __launch_bounds__(256) void qkv_partial_k(
    const float* __restrict__ x, const float* __restrict__ wq,
    const float* __restrict__ wk, const float* __restrict__ wv,
    float* __restrict__ part) {
  const int cb = blockIdx.x % 14;
  const int kc = blockIdx.x / 14;
  const int c0 = cb * 512 + threadIdx.x * 2;   // first of 2 owned columns

  const float* w; int OD, j;
  if (c0 < 5120)      { w = wq; OD = 5120; j = c0; }
  else if (c0 < 6144) { w = wk; OD = 1024; j = c0 - 5120; }
  else                { w = wv; OD = 1024; j = c0 - 6144; }

  const int i0 = kc * KCH;
  float ax[BS], ay[BS];
#pragma unroll
  for (int b = 0; b < BS; ++b) { ax[b] = 0.f; ay[b] = 0.f; }

  const float* wp = w + (size_t)i0 * OD + j;
  const float* xp = x + i0;
#pragma unroll 4
  for (int ii = 0; ii < KCH; ++ii) {
    const float2 wv2 = *(const float2*)&wp[(size_t)ii * OD];
#pragma unroll
    for (int b = 0; b < BS; ++b) {
      const float xb = xp[b * DIM + ii];   // wave-uniform -> scalar load
      ax[b] = fmaf(xb, wv2.x, ax[b]);
      ay[b] = fmaf(xb, wv2.y, ay[b]);
    }
  }
#pragma unroll
  for (int b = 0; b < BS; ++b)
    *(float2*)&part[((size_t)kc * BS + b) * ODQKV + c0] = make_float2(ax[b], ay[b]);
}

// ---------------------------------------------------------------------------
// Phase A2: reduce partials, add bias, apply RoPE (pos 4095), fold 1/sqrt(128)
// into q.
// ---------------------------------------------------------------------------
__global__ __launch_bounds__(256) void qkv_reduce_k(
    const float* __restrict__ part, const float* __restrict__ bq,
    const float* __restrict__ bk, const float* __restrict__ bv,
    const float* __restrict__ fc, float* __restrict__ qws,
    float* __restrict__ kws, float* __restrict__ vws) {
  int g = blockIdx.x * 256 + threadIdx.x;
  if (g >= BS * (ODQKV / 2)) return;
  int b  = g / (ODQKV / 2);
  int cp = g - b * (ODQKV / 2);
  int c0 = cp * 2;

  float sx = 0.f, sy = 0.f;
  for (int kc = 0; kc < NKC; ++kc) {
    const float2 p = *(const float2*)&part[((size_t)kc * BS + b) * ODQKV + c0];
    sx += p.x; sy += p.y;
  }

  const float scale = 0.088388347648318447f;  // 1/sqrt(128)
  if (c0 < 5120) {
    sx += bq[c0]; sy += bq[c0 + 1];
    int jf = (c0 & 127) >> 1;
    float cs = fc[2 * jf], sn = fc[2 * jf + 1];
    qws[b * DIM + c0]     = (sx * cs - sy * sn) * scale;
    qws[b * DIM + c0 + 1] = (sx * sn + sy * cs) * scale;
  } else if (c0 < 6144) {
    int jj = c0 - 5120;
    sx += bk[jj]; sy += bk[jj + 1];
    int jf = (jj & 127) >> 1;
    float cs = fc[2 * jf], sn = fc[2 * jf + 1];
    kws[b * NKV * HD + jj]     = sx * cs - sy * sn;
    kws[b * NKV * HD + jj + 1] = sx * sn + sy * cs;
  } else {
    int jj = c0 - 6144;
    vws[b * NKV * HD + jj]     = sx + bv[jj];
    vws[b * NKV * HD + jj + 1] = sy + bv[jj + 1];
  }
}

// ---------------------------------------------------------------------------
// Phase B: flash-decode partials, DENSE-STREAMING layout.
// Block = (b, t-chunk of 64), 8 waves; wave w owns kv-head h=w. The 8 waves
// together read every byte of each 4-KB [t][*][*] cache row -> page-friendly
// HBM streaming (vs 512B-per-4KB per-head stride).
// Lane L: half = L>>5 picks t = t0+2i+half; j32 = L&31 owns d=[4*j32,4*j32+4).
// One float4/lane/row: each load instruction covers 1 KB contiguous (2 rows).
// Dot: 4 FMA/head + 5-stage butterfly within 32-lane half. Branchless online
// softmax per half; xor-32 merge at end. No LDS. Tail t=4095 peeled.
// ---------------------------------------------------------------------------
__global__ __launch_bounds__(512) void attn_partial_k(
    const float* __restrict__ ck, const float* __restrict__ cv,
    const float* __restrict__ qws, const float* __restrict__ kws,
    const float* __restrict__ vws, float* __restrict__ pM,
    float* __restrict__ pL, float* __restrict__ pO) {
  const int blk   = blockIdx.x;
  const int chunk = blk & (NCHB - 1);
  const int b     = blk / NCHB;
  const int w     = threadIdx.x >> 6;    // wave index = kv head
  const int lane  = threadIdx.x & 63;
  const int half  = lane >> 5;           // t parity within a step
  const int j32   = lane & 31;           // d-chunk [4*j32, 4*j32+4)
  const int t0    = chunk * CH_T;

  float4 q[NREP];
#pragma unroll
  for (int r = 0; r < NREP; ++r)
    q[r] = *(const float4*)&qws[b * DIM + (w * NREP + r) * HD + 4 * j32];

  float m[NREP], l[NREP];
  float4 o[NREP];
#pragma unroll
  for (int r = 0; r < NREP; ++r) {
    m[r] = -1e30f; l[r] = 0.f; o[r] = make_float4(0.f, 0.f, 0.f, 0.f);
  }

  const float* kbase = &ck[((size_t)b * KLEN * NKV + w) * HD];
  const float* vbase = &cv[((size_t)b * KLEN * NKV + w) * HD];

  auto step = [&](const float4 k4, const float4 v4) {
    float s[NREP];
#pragma unroll
    for (int r = 0; r < NREP; ++r)
      s[r] = q[r].x * k4.x + q[r].y * k4.y + q[r].z * k4.z + q[r].w * k4.w;
#pragma unroll
    for (int off = 1; off < 32; off <<= 1) {
#pragma unroll
      for (int r = 0; r < NREP; ++r) s[r] += __shfl_xor(s[r], off, 64);
    }
#pragma unroll
    for (int r = 0; r < NREP; ++r) {
      float mn = fmaxf(m[r], s[r]);
      float p  = __expf(s[r] - mn);
      float rs = __expf(m[r] - mn);
      l[r] = fmaf(l[r], rs, p);
      o[r].x = fmaf(p, v4.x, o[r].x * rs);
      o[r].y = fmaf(p, v4.y, o[r].y * rs);
      o[r].z = fmaf(p, v4.z, o[r].z * rs);
      o[r].w = fmaf(p, v4.w, o[r].w * rs);
      m[r] = mn;
    }
  };

  const bool tailb = (chunk == NCHB - 1);
  const int  niter = tailb ? (CH_T / 2 - 1) : (CH_T / 2);   // 31 or 32 steps

  const float* kp = kbase + (size_t)(t0 + half) * (NKV * HD) + 4 * j32;
  const float* vp = vbase + (size_t)(t0 + half) * (NKV * HD) + 4 * j32;
#pragma unroll 4
  for (int i = 0; i < niter; ++i) {
    const float4 k4 = *(const float4*)kp;
    const float4 v4 = *(const float4*)vp;
    kp += 2 * NKV * HD;
    vp += 2 * NKV * HD;
    step(k4, v4);
  }
  if (tailb) {
    const int t = t0 + CH_T - 2 + half;            // 4094, 4095
    const float* kr = (t == NEWT) ? &kws[(b * NKV + w) * HD]
                                  : kbase + (size_t)t * (NKV * HD);
    const float* vr = (t == NEWT) ? &vws[(b * NKV + w) * HD]
                                  : vbase + (size_t)t * (NKV * HD);
    step(*(const float4*)(kr + 4 * j32), *(const float4*)(vr + 4 * j32));
  }

  // merge the two t-parity halves (lanes L and L^32 hold the same d-range)
#pragma unroll
  for (int r = 0; r < NREP; ++r) {
    float  mo = __shfl_xor(m[r], 32, 64);
    float  lo = __shfl_xor(l[r], 32, 64);
    float4 oo;
    oo.x = __shfl_xor(o[r].x, 32, 64);
    oo.y = __shfl_xor(o[r].y, 32, 64);
    oo.z = __shfl_xor(o[r].z, 32, 64);
    oo.w = __shfl_xor(o[r].w, 32, 64);
    float mn = fmaxf(m[r], mo);
    float ea = __expf(m[r] - mn);
    float eb = __expf(mo - mn);
    l[r] = l[r] * ea + lo * eb;
    o[r].x = o[r].x * ea + oo.x * eb;
    o[r].y = o[r].y * ea + oo.y * eb;
    o[r].z = o[r].z * ea + oo.z * eb;
    o[r].w = o[r].w * ea + oo.w * eb;
    m[r] = mn;
  }

  const int pb = (b * NKV + w) * NCHB + chunk;
  if (half == 0) {
#pragma unroll
    for (int r = 0; r < NREP; ++r)
      *(float4*)&pO[((size_t)pb * NREP + r) * HD + 4 * j32] = o[r];
    if (j32 == 0) {
#pragma unroll
      for (int r = 0; r < NREP; ++r) {
        pM[pb * NREP + r] = m[r];
        pL[pb * NREP + r] = l[r];
      }
    }
  }
}

// ---------------------------------------------------------------------------
// Phase B2: combine NPART partials per (b,h) with exp rescale.
// ---------------------------------------------------------------------------
__global__ __launch_bounds__(256) void attn_combine_k(
    const float* __restrict__ pM, const float* __restrict__ pL,
    const float* __restrict__ pO, float* __restrict__ attn) {
  const int bh  = blockIdx.x;
  const int h   = bh & (NKV - 1);
  const int b   = bh / NKV;
  const int tid = threadIdx.x;
  __shared__ float ml[NREP * NPART], ll[NREP * NPART];
  __shared__ float wgt[NREP * NPART];
  __shared__ float Linv[NREP];

  for (int idx = tid; idx < NREP * NPART; idx += 256) {
    int r = idx / NPART, w = idx - r * NPART;
    ml[idx] = pM[(bh * NPART + w) * NREP + r];
    ll[idx] = pL[(bh * NPART + w) * NREP + r];
  }
  __syncthreads();
  for (int idx = tid; idx < NREP * NPART; idx += 256) {
    int r = idx / NPART;
    float M = -1e30f;
    for (int w = 0; w < NPART; ++w) M = fmaxf(M, ml[r * NPART + w]);
    float e = __expf(ml[idx] - M);
    wgt[idx] = e;
    ll[idx] *= e;
  }
  __syncthreads();
  if (tid < NREP) {
    float L = 0.f;
    for (int w = 0; w < NPART; ++w) L += ll[tid * NPART + w];
    Linv[tid] = 1.f / L;
  }
  __syncthreads();

  for (int oidx = tid; oidx < NREP * HD; oidx += 256) {
    int r = oidx >> 7, d = oidx & 127;
    float acc = 0.f;
    for (int w = 0; w < NPART; ++w)
      acc += wgt[r * NPART + w] * pO[((size_t)(bh * NPART + w) * NREP + r) * HD + d];
    attn[b * DIM + (h * NREP + r) * HD + d] = acc * Linv[r];
  }
}

// ---------------------------------------------------------------------------
// Phase C: output projection GEMV (split-K, 2 cols/thread) + reduce with bias.
// ---------------------------------------------------------------------------
__global__ __launch_bounds__(256) void out_partial_k(
    const float* __restrict__ attn, const float* __restrict__ wo,
    float* __restrict__ part) {
  const int cb = blockIdx.x % 10;
  const int kc = blockIdx.x / 10;
  const int c0 = cb * 512 + threadIdx.x * 2;

  const int i0 = kc * KCH;
  float ax[BS], ay[BS];
#pragma unroll
  for (int b = 0; b < BS; ++b) { ax[b] = 0.f; ay[b] = 0.f; }

  const float* wp = wo + (size_t)i0 * DIM + c0;
  const float* xp = attn + i0;
#pragma unroll 4
  for (int ii = 0; ii < KCH; ++ii) {
    const float2 wv2 = *(const float2*)&wp[(size_t)ii * DIM];
#pragma unroll
    for (int b = 0; b < BS; ++b) {
      const float xb = xp[b * DIM + ii];   // wave-uniform -> scalar load
      ax[b] = fmaf(xb, wv2.x, ax[b]);
      ay[b] = fmaf(xb, wv2.y, ay[b]);
    }
  }
#pragma unroll
  for (int b = 0; b < BS; ++b)
    *(float2*)&part[((size_t)kc * BS + b) * DIM + c0] = make_float2(ax[b], ay[b]);
}

__global__ __launch_bounds__(256) void out_reduce_k(
    const float* __restrict__ part, const float* __restrict__ bo,
    float* __restrict__ out) {
  int g = blockIdx.x * 256 + threadIdx.x;
  if (g >= BS * DIM) return;
  int b = g / DIM, c = g - b * DIM;
  float s = 0.f;
  for (int kc = 0; kc < NKC; ++kc) s += part[((size_t)kc * BS + b) * DIM + c];
  out[g] = s + bo[c];
}

// ---------------------------------------------------------------------------
extern "C" void kernel_launch(void* const* d_in, const int* in_sizes, int n_in,
                              void* d_out, int out_size, void* d_ws, size_t ws_size,
                              hipStream_t stream) {
  const float* x  = (const float*)d_in[0];
  // d_in[1] = start_pos (hardcoded 4095 per problem constants)
  const float* fc = (const float*)d_in[2];
  const float* ck = (const float*)d_in[3];
  const float* cv = (const float*)d_in[4];
  const float* wq = (const float*)d_in[5];
  const float* bq = (const float*)d_in[6];
  const float* wk = (const float*)d_in[7];
  const float* bk = (const float*)d_in[8];
  const float* wv = (const float*)d_in[9];
  const float* bv = (const float*)d_in[10];
  const float* wo = (const float*)d_in[11];
  const float* bo = (const float*)d_in[12];

  float* ws      = (float*)d_ws;
  float* qws     = ws + WS_Q;
  float* kws     = ws + WS_K;
  float* vws     = ws + WS_V;
  float* attn    = ws + WS_ATTN;
  float* scratch = ws + WS_SCRATCH;

  // Phase A: QKV projection
  qkv_partial_k<<<14 * NKC, 256, 0, stream>>>(x, wq, wk, wv, scratch);
  qkv_reduce_k<<<(BS * (ODQKV / 2) + 255) / 256, 256, 0, stream>>>(
      scratch, bq, bk, bv, fc, qws, kws, vws);

  // Phase B: attention (scratch reused for softmax partials)
  float* pM = scratch;                          // 64*NPART*NREP
  float* pL = pM + 64 * NPART * NREP;
  float* pO = pL + 64 * NPART * NREP;           // 64*NPART*NREP*HD floats
  attn_partial_k<<<BS * NCHB, 512, 0, stream>>>(ck, cv, qws, kws, vws, pM, pL, pO);
  attn_combine_k<<<64, 256, 0, stream>>>(pM, pL, pO, attn);

  // Phase C: output projection (scratch reused for GEMV partials)
  out_partial_k<<<10 * NKC, 256, 0, stream>>>(attn, wo, scratch);
  out_reduce_k<<<(BS * DIM + 255) / 256, 256, 0, stream>>>(scratch, bo, (float*)d_out);
}